// Round 20
// baseline (1269.973 us; speedup 1.0000x reference)
//
#include <hip/hip_runtime.h>

#define BT     32768
#define HIDDEN 512
#define DDIM   256
#define KCODE  1024
#define NQUANT 8

typedef _Float16 f16;
typedef _Float16 f16x8 __attribute__((ext_vector_type(8)));
typedef float f32x4 __attribute__((ext_vector_type(4)));
typedef float f32x8 __attribute__((ext_vector_type(8)));

#define LO_SCALE 64.0f
#define LO_INV   0.015625f

// ---------------------------------------------------------------------------
// codebook prep v3: fragment-major for the wc-split sweep + cnorm.
// Per quantizer q: fragment address ((q*1024)+(wc*512)+(chunk*16)+f)*512,
// f = part*8+s; element lane*8+i (lane=li*16+lj) holds
//   part==0 ? hi(cb[code][d]) : lo(cb[code][d])*64
// with code = wc*512 + chunk*16 + lj, d = s*32+li*8+i. grid NQ*K x 256.
// ---------------------------------------------------------------------------
__global__ __launch_bounds__(256) void cb_prep3(const float* __restrict__ cb,
                                                f16* __restrict__ cbfrag,
                                                float* __restrict__ cnorm) {
  __shared__ float red[256];
  const int gc = blockIdx.x;                     // global code
  const int q = gc >> 10, c = gc & 1023;
  const int wc = c >> 9, rem = c & 511;
  const int chunk = rem >> 4, lj = rem & 15;
  const int d = threadIdx.x;
  const int s = d >> 5, li = (d >> 3) & 3, i = d & 7;
  const int lane = li * 16 + lj;

  const float v = cb[(size_t)gc * DDIM + d];
  const f16 hi = (f16)v;
  const f16 lo = (f16)((v - (float)hi) * LO_SCALE);
  const size_t base = ((size_t)q * 1024 + wc * 512 + chunk * 16) * 512;
  cbfrag[base + (size_t)s * 512 + lane * 8 + i] = hi;          // part 0
  cbfrag[base + (size_t)(8 + s) * 512 + lane * 8 + i] = lo;    // part 1

  red[d] = v * v;
  __syncthreads();
  for (int t = 128; t > 0; t >>= 1) {
    if (d < t) red[d] += red[d + t];
    __syncthreads();
  }
  if (d == 0) cnorm[gc] = red[0];
}

// ---------------------------------------------------------------------------
// weight -> f16 hi/lo ext: Wext[n][0..K-1]=hi, [K..2K-1]=lo*64
// ---------------------------------------------------------------------------
__global__ __launch_bounds__(256) void bext_conv(const float* __restrict__ W,
                                                 f16* __restrict__ Wext,
                                                 int N, int K) {
  const int idx = blockIdx.x * 256 + threadIdx.x;
  if (idx >= N * K) return;
  const int n = idx / K, k = idx - n * K;
  const float v = W[idx];
  const f16 hi = (f16)v;
  Wext[(size_t)n * 2 * K + k] = hi;
  Wext[(size_t)n * 2 * K + K + k] = (f16)((v - (float)hi) * LO_SCALE);
}

__global__ void zero2(float* commitAcc, unsigned* bar) {
  commitAcc[0] = 0.f;
  bar[0] = 0u;
}

__global__ void finalize_com(const float* __restrict__ a, float* __restrict__ o) {
  o[0] = a[0] * (1.0f / (float)((size_t)NQUANT * BT * DDIM));
}

// ---------------------------------------------------------------------------
// Fused 8-step RVQ v16: wc-split M=32 + fragment-major (retry of R16's
// 2-waves/SIMD experiment below the VGPR co-residency threshold: R16 failed
// at 212 VGPR; fragment-major addressing measured 184 in R19 and this
// kernel's per-wave state is smaller still).
// 512 blocks x 256 thr; waves = 2 wr token-groups x 2 wc code-halves.
// Wave owns 32 tokens in af[2][16], sweeps its 512-code half in 32 chunks
// of 16 codes. Per chunk both halves staged: 32 fragments x 1 KB = 32 KB,
// dbuf 64 KB; merge/reduce scratch overlaid -> LDS exactly 65536 B.
// Phase barrier is SELF-DISABLING: cap 1024 spins; first timeout disables
// all later spins for this block (worst case ~120us once, not 7ms).
// accM (hi*hi) / accC (cross, x64); d = cnorm - 2*(accM + accC/64).
// ---------------------------------------------------------------------------
__global__ __launch_bounds__(256) void rvq_fused16(
    const f16* __restrict__ rext, const f16* __restrict__ cbfrag,
    const float* __restrict__ cbf32, const float* __restrict__ cnorm,
    float* __restrict__ qsum, float* __restrict__ q1, float* __restrict__ q2,
    float* __restrict__ commitAcc, unsigned* __restrict__ bar) {
  __shared__ __align__(16) unsigned char smem[2 * 32 * 512 * 2];  // 64 KB
  f16 (*Bs)[32][512] = reinterpret_cast<f16 (*)[32][512]>(smem);
  // Overlays (live only after the sweep, before next STAGE):
  float (*mv)[64] = reinterpret_cast<float (*)[64]>(smem);         // 512 B
  int   (*mi)[64] = reinterpret_cast<int (*)[64]>(smem + 512);     // 512 B
  int*   bidx     = reinterpret_cast<int*>(smem + 1024);           // 256 B
  float* redc     = reinterpret_cast<float*>(smem + 1280);         // 1 KB
  __shared__ int barok;
  const int tid = threadIdx.x;
  const int w = tid >> 6, l = tid & 63;
  const int wr = w >> 1, wc = w & 1;
  const int lj = l & 15, li = l >> 4;
  const int m0 = blockIdx.x * 64;
  if (tid == 0) barok = 1;

  // residual: af[m][s], token row = m0 + wr*32 + m*16 + lj (hi 0-7, lo 8-15)
  f16x8 af[2][16];
#pragma unroll
  for (int m = 0; m < 2; ++m) {
    const int row = m0 + wr * 32 + m * 16 + lj;
#pragma unroll
    for (int s = 0; s < 16; ++s)
      af[m][s] = *(const f16x8*)&rext[(size_t)row * 512 + s * 32 + li * 8];
  }

  float csum = 0.f;

#pragma unroll 1
  for (int nq = 0; nq < NQUANT; ++nq) {
    if (nq > 0) {
      __syncthreads();
      if (tid == 0) {
        __threadfence();
        atomicAdd(bar, 1u);
        if (barok) {
          const unsigned target = (unsigned)nq * gridDim.x;
          int spins = 0;
          while (__hip_atomic_load(bar, __ATOMIC_RELAXED,
                                   __HIP_MEMORY_SCOPE_AGENT) < target &&
                 spins < 1024) {
            ++spins;
            __builtin_amdgcn_s_sleep(4);
          }
          if (spins >= 1024) barok = 0;          // free-run from now on
        }
      }
      __syncthreads();
    }
    const f16* cbq = cbfrag + (size_t)nq * KCODE * 512;  // fragment-major
    const float* cnq = cnorm + nq * KCODE;

    // stage chunk c: 32 fragments (g = wc_h*16 + f), contiguous 1 KB each
    auto STAGE = [&](int chunk, int buf) {
#pragma unroll
      for (int q = 0; q < 8; ++q) {
        const int g = w * 8 + q;
        const int wc_h = g >> 4, f = g & 15;
        const f16* src = cbq + ((size_t)(wc_h * 512 + chunk * 16 + f) << 9) + l * 8;
        __builtin_amdgcn_global_load_lds(
            (const __attribute__((address_space(1))) void*)src,
            (__attribute__((address_space(3))) void*)&Bs[buf][g][0], 16, 0, 0);
      }
    };

    float bval[2][4]; int bidxr[2][4];
#pragma unroll
    for (int m = 0; m < 2; ++m)
#pragma unroll
      for (int j = 0; j < 4; ++j) { bval[m][j] = 3.0e38f; bidxr[m][j] = 0; }

    STAGE(0, 0);
    __syncthreads();
    int buf = 0;

#pragma unroll 1
    for (int c = 0; c < 32; ++c) {
      if (c < 31) STAGE(c + 1, buf ^ 1);
      f32x4 accM[2], accC[2];
#pragma unroll
      for (int m = 0; m < 2; ++m) {
        accM[m] = (f32x4){0.f, 0.f, 0.f, 0.f};
        accC[m] = (f32x4){0.f, 0.f, 0.f, 0.f};
      }

      // phase 1 (lo_c): frag wc*16 + 8 + s; hi_r * lo_c -> accC
#pragma unroll
      for (int s = 0; s < 8; ++s) {
        const f16x8 bf = *(const f16x8*)&Bs[buf][wc * 16 + 8 + s][l * 8];
#pragma unroll
        for (int m = 0; m < 2; ++m)
          accC[m] = __builtin_amdgcn_mfma_f32_16x16x32_f16(
              af[m][s], bf, accC[m], 0, 0, 0);
      }
      // phase 2 (hi_c, shared): frag wc*16 + s; lo_r*hi_c -> accC AND
      // hi_r*hi_c -> accM (4 MFMAs per read).
#pragma unroll
      for (int s = 0; s < 8; ++s) {
        const f16x8 bf = *(const f16x8*)&Bs[buf][wc * 16 + s][l * 8];
#pragma unroll
        for (int m = 0; m < 2; ++m) {
          accC[m] = __builtin_amdgcn_mfma_f32_16x16x32_f16(
              af[m][8 + s], bf, accC[m], 0, 0, 0);
          accM[m] = __builtin_amdgcn_mfma_f32_16x16x32_f16(
              af[m][s], bf, accM[m], 0, 0, 0);
        }
      }
      // distances + running argmin (ascending order -> first-occurrence)
      {
        const int cl = wc * 512 + c * 16 + lj;
        const float cn = cnq[cl];
#pragma unroll
        for (int m = 0; m < 2; ++m)
#pragma unroll
          for (int j = 0; j < 4; ++j) {
            const float d = cn - 2.0f * (accM[m][j] + accC[m][j] * LO_INV);
            if (d < bval[m][j]) { bval[m][j] = d; bidxr[m][j] = cl; }
          }
      }
      __syncthreads();                           // staging + buf reads done
      buf ^= 1;
    }

    // reduce over the 16-lane code axis (lexicographic (val, idx) min)
#pragma unroll
    for (int off = 1; off < 16; off <<= 1) {
#pragma unroll
      for (int m = 0; m < 2; ++m)
#pragma unroll
        for (int j = 0; j < 4; ++j) {
          const float ov = __shfl_xor(bval[m][j], off);
          const int oi = __shfl_xor(bidxr[m][j], off);
          if (ov < bval[m][j] || (ov == bval[m][j] && oi < bidxr[m][j])) {
            bval[m][j] = ov; bidxr[m][j] = oi;
          }
        }
    }
    if (lj == 0) {
#pragma unroll
      for (int m = 0; m < 2; ++m)
#pragma unroll
        for (int j = 0; j < 4; ++j) {
          const int tok = wr * 32 + m * 16 + li * 4 + j;
          mv[wc][tok] = bval[m][j]; mi[wc][tok] = bidxr[m][j];
        }
    }
    __syncthreads();
    if (tid < 64) {                              // wc0 codes < wc1 codes
      float v0 = mv[0][tid]; int i0 = mi[0][tid];
      if (mv[1][tid] < v0) { v0 = mv[1][tid]; i0 = mi[1][tid]; }
      bidx[tid] = i0;
    }
    __syncthreads();

    // in-register residual update (both wc copies) + q1/q2 (wc==0 only)
#pragma unroll
    for (int m = 0; m < 2; ++m) {
      const int tokl = wr * 32 + m * 16 + lj;
      const int code = bidx[tokl];
      const float* qrow = cbf32 + ((size_t)nq * KCODE + code) * DDIM;
#pragma unroll
      for (int s = 0; s < 8; ++s) {
        const f32x8 qv = *(const f32x8*)&qrow[s * 32 + li * 8];
        f16x8 h = af[m][s], lo = af[m][8 + s];
#pragma unroll
        for (int i = 0; i < 8; ++i) {
          const float rold = (float)h[i] + (float)lo[i] * LO_INV;
          const float diff = qv[i] - rold;
          if (wc == 0) csum += diff * diff;
          const float rnew = rold - qv[i];
          const f16 nh = (f16)rnew;
          h[i] = nh;
          lo[i] = (f16)((rnew - (float)nh) * LO_SCALE);
        }
        af[m][s] = h; af[m][8 + s] = lo;
        if (wc == 0 && nq == 0)
          *(f32x8*)&q1[(size_t)(m0 + tokl) * DDIM + s * 32 + li * 8] = qv;
        if (wc == 0 && nq == 1)
          *(f32x8*)&q2[(size_t)(m0 + tokl) * DDIM + s * 32 + li * 8] = qv;
      }
    }
    __syncthreads();                             // bidx consumed before restage
  }

  // qsum = h - r_final (h re-read from untouched rext); wc==0 writes
  if (wc == 0) {
#pragma unroll
    for (int m = 0; m < 2; ++m) {
      const int row = m0 + wr * 32 + m * 16 + lj;
#pragma unroll
      for (int s = 0; s < 8; ++s) {
        const f16x8 hh = *(const f16x8*)&rext[(size_t)row * 512 + s * 32 + li * 8];
        const f16x8 hl = *(const f16x8*)&rext[(size_t)row * 512 + 256 + s * 32 + li * 8];
        f32x8 o;
#pragma unroll
        for (int i = 0; i < 8; ++i)
          o[i] = ((float)hh[i] + (float)hl[i] * LO_INV) -
                 ((float)af[m][s][i] + (float)af[m][8 + s][i] * LO_INV);
        *(f32x8*)&qsum[(size_t)row * DDIM + s * 32 + li * 8] = o;
      }
    }
  }

  redc[tid] = csum;
  __syncthreads();
  for (int s = 128; s > 0; s >>= 1) {
    if (tid < s) redc[tid] += redc[tid + s];
    __syncthreads();
  }
  if (tid == 0) atomicAdd(commitAcc, redc[0]);
}

// ---------------------------------------------------------------------------
// Projection v3 (builtin MFMA — R9/R12/R13/R17/R19-bench-passing, unchanged).
// ---------------------------------------------------------------------------
template <int K, bool WEXT>
__global__ __launch_bounds__(512) void proj3(
    const float* __restrict__ A, const f16* __restrict__ Bext,
    const float* __restrict__ bias, float* __restrict__ Cout,
    f16* __restrict__ CextOut, int Ntot) {
  __shared__ __align__(16) f16 Bs[128][512];     // 128 KB
  const int tid = threadIdx.x;
  const int w = tid >> 6, l = tid & 63;
  const int lj = l & 15, li = l >> 4;
  const int m0 = blockIdx.x * 128;
  const int n0 = blockIdx.y * 128;
  const int row_t = m0 + w * 16 + lj;
  const int key = (lj & 7) << 4;

  f32x4 acc[8], acc2[8];
#pragma unroll
  for (int n = 0; n < 8; ++n) {
    acc[n] = (f32x4){0.f, 0.f, 0.f, 0.f};
    acc2[n] = (f32x4){0.f, 0.f, 0.f, 0.f};
  }

#pragma unroll 1
  for (int p = 0; p < K / 256; ++p) {
    __syncthreads();
#pragma unroll
    for (int q = 0; q < 16; ++q) {
      const int r = w * 16 + q;
      const int nrow = n0 + r;
      const int byteoff = (l * 16) ^ ((r & 7) << 4);
      const char* hi_base =
          (const char*)Bext + ((size_t)nrow * 2 * K + p * 256) * 2;
      const char* lo_base =
          (const char*)Bext + ((size_t)nrow * 2 * K + K + p * 256) * 2;
      const char* src = (byteoff < 512) ? hi_base + byteoff
                                        : lo_base + (byteoff - 512);
      __builtin_amdgcn_global_load_lds(
          (const __attribute__((address_space(1))) void*)src,
          (__attribute__((address_space(3))) void*)&Bs[r][0], 16, 0, 0);
    }
    f16x8 ahi[8], alo[8];
#pragma unroll
    for (int s = 0; s < 8; ++s) {
      const f32x8 v = *(const f32x8*)&A[(size_t)row_t * K + p * 256 + s * 32 + li * 8];
      f16x8 h, lo;
#pragma unroll
      for (int i = 0; i < 8; ++i) {
        const f16 hh = (f16)v[i];
        h[i] = hh;
        lo[i] = (f16)((v[i] - (float)hh) * LO_SCALE);
      }
      ahi[s] = h; alo[s] = lo;
    }
    __syncthreads();

#pragma unroll
    for (int t = 0; t < 12; ++t) {
      const int tl = (t < 4) ? t : (t < 8 ? t - 4 : t - 8);
      const int roff = (t < 4) ? 512 : 0;
#pragma unroll
      for (int n = 0; n < 8; ++n) {
        const int rr = n * 16 + lj;
#pragma unroll
        for (int kk = 0; kk < 2; ++kk) {
          const int boff = roff + tl * 128 + kk * 64 + li * 16;
          const f16x8 bf = *(const f16x8*)((const char*)&Bs[rr][0] + (boff ^ key));
          if (t < 4)
            acc2[n] = __builtin_amdgcn_mfma_f32_16x16x32_f16(ahi[2 * tl + kk], bf, acc2[n], 0, 0, 0);
          else if (t < 8)
            acc2[n] = __builtin_amdgcn_mfma_f32_16x16x32_f16(alo[2 * tl + kk], bf, acc2[n], 0, 0, 0);
          else
            acc[n] = __builtin_amdgcn_mfma_f32_16x16x32_f16(ahi[2 * tl + kk], bf, acc[n], 0, 0, 0);
        }
      }
    }
  }

#pragma unroll
  for (int n = 0; n < 8; ++n) {
    const int ncol = n0 + n * 16 + lj;
    const float bb = bias[ncol];
#pragma unroll
    for (int j = 0; j < 4; ++j) {
      const int tok = m0 + w * 16 + li * 4 + j;
      const float vv = acc[n][j] + acc2[n][j] * LO_INV + bb;
      if (WEXT) {
        const f16 hh = (f16)vv;
        CextOut[(size_t)tok * 512 + ncol] = hh;
        CextOut[(size_t)tok * 512 + 256 + ncol] = (f16)((vv - (float)hh) * LO_SCALE);
      } else {
        Cout[(size_t)tok * Ntot + ncol] = vv;
      }
    }
  }
}

extern "C" void kernel_launch(void* const* d_in, const int* in_sizes, int n_in,
                              void* d_out, int out_size, void* d_ws, size_t ws_size,
                              hipStream_t stream) {
  (void)in_sizes; (void)n_in; (void)out_size; (void)ws_size;
  const float* x     = (const float*)d_in[0];
  const float* W_in  = (const float*)d_in[1];
  const float* b_in  = (const float*)d_in[2];
  const float* W_out = (const float*)d_in[3];
  const float* b_out = (const float*)d_in[4];
  const float* cbs   = (const float*)d_in[5];

  float* out = (float*)d_out;                        // [BT, HIDDEN]
  float* q1  = out + (size_t)BT * HIDDEN;            // [BT, DDIM]
  float* q2  = q1 + (size_t)BT * DDIM;               // [BT, DDIM]
  float* com = q2 + (size_t)BT * DDIM;               // [1]

  f16*   rext      = (f16*)d_ws;                          // [BT][512]   32 MB
  float* qsum      = (float*)(rext + (size_t)BT * 512);   // [BT][256]   32 MB
  f16*   cbfrag    = (f16*)(qsum + (size_t)BT * DDIM);    // [8192][512]  8 MB
  f16*   W_inext   = cbfrag + (size_t)NQUANT * KCODE * 512; // [256][1024] 512 KB
  f16*   W_outext  = W_inext + (size_t)DDIM * 1024;        // [512][512]  512 KB
  float* cnorm     = (float*)(W_outext + (size_t)HIDDEN * 512);  // [NQ*K]
  float* commitAcc = cnorm + NQUANT * KCODE;
  unsigned* bar    = (unsigned*)(commitAcc + 1);

  cb_prep3<<<NQUANT * KCODE, 256, 0, stream>>>(cbs, cbfrag, cnorm);
  bext_conv<<<(DDIM * HIDDEN + 255) / 256, 256, 0, stream>>>(W_in, W_inext, DDIM, HIDDEN);
  bext_conv<<<(HIDDEN * DDIM + 255) / 256, 256, 0, stream>>>(W_out, W_outext, HIDDEN, DDIM);
  proj3<HIDDEN, true><<<dim3(BT / 128, DDIM / 128), 512, 0, stream>>>(
      x, W_inext, b_in, nullptr, rext, DDIM);
  zero2<<<1, 1, 0, stream>>>(commitAcc, bar);
  rvq_fused16<<<BT / 64, 256, 0, stream>>>(rext, cbfrag, cbs, cnorm,
                                           qsum, q1, q2, commitAcc, bar);
  proj3<DDIM, false><<<dim3(BT / 128, HIDDEN / 128), 512, 0, stream>>>(
      qsum, W_outext, b_out, out, nullptr, HIDDEN);
  finalize_com<<<1, 1, 0, stream>>>(commitAcc, com);
}

// Round 21
// 703.482 us; speedup vs baseline: 1.8053x; 1.8053x over previous
//
#include <hip/hip_runtime.h>

#define BT     32768
#define HIDDEN 512
#define DDIM   256
#define KCODE  1024
#define NQUANT 8

typedef _Float16 f16;
typedef _Float16 f16x8 __attribute__((ext_vector_type(8)));
typedef float f32x4 __attribute__((ext_vector_type(4)));
typedef float f32x8 __attribute__((ext_vector_type(8)));

#define LO_SCALE 64.0f
#define LO_INV   0.015625f

// ---------------------------------------------------------------------------
// codebook prep (R18/R19-proven): FRAGMENT-MAJOR ext layout + cnorm.
// For quantizer q, chunk of 64 codes, fragment f = part*32 + s*4 + n (1 KB,
// lane-linear): element lane*8+i holds part==0 ? hi : lo*64 of cb[code][d],
// code = chunk*64 + n*16 + lj, d = s*32 + li*8 + i, lane = li*16 + lj.
// ---------------------------------------------------------------------------
__global__ __launch_bounds__(256) void cb_prep2(const float* __restrict__ cb,
                                                f16* __restrict__ cbfrag,
                                                float* __restrict__ cnorm) {
  __shared__ float red[256];
  const int gc = blockIdx.x;
  const int q = gc >> 10, c = gc & 1023;
  const int chunk = c >> 6, cc = c & 63;
  const int n = cc >> 4, lj = cc & 15;
  const int d = threadIdx.x;
  const int s = d >> 5, li = (d >> 3) & 3, i = d & 7;
  const int lane = li * 16 + lj;

  const float v = cb[(size_t)gc * DDIM + d];
  const f16 hi = (f16)v;
  const f16 lo = (f16)((v - (float)hi) * LO_SCALE);
  const size_t base = ((size_t)q * 1024 + chunk * 64) * 512;
  cbfrag[base + (size_t)(s * 4 + n) * 512 + lane * 8 + i] = hi;
  cbfrag[base + (size_t)(32 + s * 4 + n) * 512 + lane * 8 + i] = lo;

  red[d] = v * v;
  __syncthreads();
  for (int t = 128; t > 0; t >>= 1) {
    if (d < t) red[d] += red[d + t];
    __syncthreads();
  }
  if (d == 0) cnorm[gc] = red[0];
}

// ---------------------------------------------------------------------------
// weight -> f16 hi/lo ext: Wext[n][0..K-1]=hi, [K..2K-1]=lo*64
// ---------------------------------------------------------------------------
__global__ __launch_bounds__(256) void bext_conv(const float* __restrict__ W,
                                                 f16* __restrict__ Wext,
                                                 int N, int K) {
  const int idx = blockIdx.x * 256 + threadIdx.x;
  if (idx >= N * K) return;
  const int n = idx / K, k = idx - n * K;
  const float v = W[idx];
  const f16 hi = (f16)v;
  Wext[(size_t)n * 2 * K + k] = hi;
  Wext[(size_t)n * 2 * K + K + k] = (f16)((v - (float)hi) * LO_SCALE);
}

__global__ void zero2(float* commitAcc, unsigned* bar) {
  commitAcc[0] = 0.f;
  bar[0] = 0u;
}

__global__ void finalize_com(const float* __restrict__ a, float* __restrict__ o) {
  o[0] = a[0] * (1.0f / (float)((size_t)NQUANT * BT * DDIM));
}

// ---------------------------------------------------------------------------
// Bounded-spin grid phase barrier (cache-phasing only; timeout-safe).
// grid 256 = 1 block/CU co-resident (R13/R19-proven operating point).
// ---------------------------------------------------------------------------
__device__ __forceinline__ void phase_barrier(unsigned* bar, unsigned gen,
                                              unsigned nblk) {
  __syncthreads();
  if (threadIdx.x == 0) {
    __threadfence();
    atomicAdd(bar, 1u);
    const unsigned target = gen * nblk;
    int spins = 0;
    while (__hip_atomic_load(bar, __ATOMIC_RELAXED, __HIP_MEMORY_SCOPE_AGENT) < target &&
           spins < 4096) {
      ++spins;
      __builtin_amdgcn_s_sleep(4);
    }
  }
  __syncthreads();
}

// ---------------------------------------------------------------------------
// Fused 8-step RVQ v17: M=16/wave x 8 waves (2 waves/SIMD TLP — the only
// co-residency-valid multi-wave cell) + R19's fragment-major layout
// (conflict-free lane-linear ds_reads, coalesced 1 KB staging) + pair-split
// accM/accC hi_c sharing (64 reads/chunk/wave, -33% vs R9's 96, with acc
// held to 16 regs so total stays within the 512-thread 128-VGPR cap that
// R9 proved spill-free).
// 256 blocks x 512 thr; wave w owns tokens [m0+w*16,+16) in af[16]
// (hi 0-7, lo 8-15; 64 VGPR); sweeps all 1024 codes in 16 chunks of 64.
// Per chunk, per n-pair: phase1 lo_c (1 MFMA/read -> accC), phase2 hi_c
// (2 MFMA/read -> accC,accM). d = cnorm - 2*(accM + accC/64).
// ---------------------------------------------------------------------------
__global__ __launch_bounds__(512) void rvq_fused17(
    const f16* __restrict__ rext, const f16* __restrict__ cbfrag,
    const float* __restrict__ cbf32, const float* __restrict__ cnorm,
    float* __restrict__ qsum, float* __restrict__ q1, float* __restrict__ q2,
    float* __restrict__ commitAcc, unsigned* __restrict__ bar) {
  __shared__ __align__(16) f16 Bs[2][64][512];   // 128 KB
  __shared__ float redc[512];
  const int tid = threadIdx.x;
  const int w = tid >> 6, l = tid & 63;          // w = 0..7
  const int lj = l & 15, li = l >> 4;
  const int m0 = blockIdx.x * 128;
  const int row = m0 + w * 16 + lj;              // this lane's token row

  // residual: af[s], hi slices 0-7, lo 8-15 (d = s*32 + li*8)
  f16x8 af[16];
#pragma unroll
  for (int s = 0; s < 16; ++s)
    af[s] = *(const f16x8*)&rext[(size_t)row * 512 + s * 32 + li * 8];

  float csum = 0.f;

#pragma unroll 1
  for (int nq = 0; nq < NQUANT; ++nq) {
    if (nq > 0) phase_barrier(bar, (unsigned)nq, gridDim.x);
    const f16* cbq = cbfrag + (size_t)nq * KCODE * 512;  // fragment-major
    const float* cnq = cnorm + nq * KCODE;

    // stage chunk c: fragment f <- contiguous 1 KB, lane-linear (8/wave)
    auto STAGE = [&](int chunk, int buf) {
#pragma unroll
      for (int q = 0; q < 8; ++q) {
        const int f = w * 8 + q;
        const f16* src = cbq + ((size_t)(chunk * 64 + f) << 9) + l * 8;
        __builtin_amdgcn_global_load_lds(
            (const __attribute__((address_space(1))) void*)src,
            (__attribute__((address_space(3))) void*)&Bs[buf][f][0], 16, 0, 0);
      }
    };

    float bval[4]; int bidxr[4];
#pragma unroll
    for (int j = 0; j < 4; ++j) { bval[j] = 3.0e38f; bidxr[j] = 0; }

    STAGE(0, 0);
    __syncthreads();
    int buf = 0;

#pragma unroll 1
    for (int c = 0; c < 16; ++c) {
      if (c < 15) STAGE(c + 1, buf ^ 1);

#pragma unroll
      for (int pair = 0; pair < 2; ++pair) {
        f32x4 accM[2], accC[2];
#pragma unroll
        for (int np = 0; np < 2; ++np) {
          accM[np] = (f32x4){0.f, 0.f, 0.f, 0.f};
          accC[np] = (f32x4){0.f, 0.f, 0.f, 0.f};
        }
        // phase 1 (lo_c, part=1): hi_r * lo_c -> accC. frag 32 + s*4 + n.
#pragma unroll
        for (int np = 0; np < 2; ++np) {
          const int n = pair * 2 + np;
#pragma unroll
          for (int s = 0; s < 8; ++s) {
            const f16x8 bf = *(const f16x8*)&Bs[buf][32 + s * 4 + n][l * 8];
            accC[np] = __builtin_amdgcn_mfma_f32_16x16x32_f16(
                af[s], bf, accC[np], 0, 0, 0);
          }
        }
        // phase 2 (hi_c, part=0, shared): lo_r*hi_c -> accC AND
        // hi_r*hi_c -> accM (2 MFMAs per read). frag s*4 + n.
#pragma unroll
        for (int np = 0; np < 2; ++np) {
          const int n = pair * 2 + np;
#pragma unroll
          for (int s = 0; s < 8; ++s) {
            const f16x8 bf = *(const f16x8*)&Bs[buf][s * 4 + n][l * 8];
            accC[np] = __builtin_amdgcn_mfma_f32_16x16x32_f16(
                af[8 + s], bf, accC[np], 0, 0, 0);
            accM[np] = __builtin_amdgcn_mfma_f32_16x16x32_f16(
                af[s], bf, accM[np], 0, 0, 0);
          }
        }
        // distances + running argmin (pair/np ascending -> first-occurrence)
#pragma unroll
        for (int np = 0; np < 2; ++np) {
          const int cl = c * 64 + (pair * 2 + np) * 16 + lj;
          const float cn = cnq[cl];
#pragma unroll
          for (int j = 0; j < 4; ++j) {
            const float d = cn - 2.0f * (accM[np][j] + accC[np][j] * LO_INV);
            if (d < bval[j]) { bval[j] = d; bidxr[j] = cl; }
          }
        }
      }
      __syncthreads();                           // staging + buf reads done
      buf ^= 1;
    }

    // reduce over the 16-lane code axis (lexicographic (val, idx) min)
#pragma unroll
    for (int off = 1; off < 16; off <<= 1) {
#pragma unroll
      for (int j = 0; j < 4; ++j) {
        const float ov = __shfl_xor(bval[j], off);
        const int oi = __shfl_xor(bidxr[j], off);
        if (ov < bval[j] || (ov == bval[j] && oi < bidxr[j])) {
          bval[j] = ov; bidxr[j] = oi;
        }
      }
    }
    // broadcast (R9-proven): token t16's code lives in lanes li==t16>>2,
    // register t16&3. This lane updates token t16 = lj.
    const int src = (lj >> 2) * 16;
    const int c0 = __shfl(bidxr[0], src);
    const int c1 = __shfl(bidxr[1], src);
    const int c2 = __shfl(bidxr[2], src);
    const int c3 = __shfl(bidxr[3], src);
    const int sel = lj & 3;
    const int myCode = (sel == 0) ? c0 : (sel == 1) ? c1 : (sel == 2) ? c2 : c3;

    // in-register residual update + q1/q2 emission (exact f32 code row)
    const float* qrow = cbf32 + ((size_t)nq * KCODE + myCode) * DDIM;
#pragma unroll
    for (int s = 0; s < 8; ++s) {
      const f32x8 qv = *(const f32x8*)&qrow[s * 32 + li * 8];
      f16x8 h = af[s], lo = af[8 + s];
#pragma unroll
      for (int i = 0; i < 8; ++i) {
        const float rold = (float)h[i] + (float)lo[i] * LO_INV;
        const float diff = qv[i] - rold;
        csum += diff * diff;
        const float rnew = rold - qv[i];
        const f16 nh = (f16)rnew;
        h[i] = nh;
        lo[i] = (f16)((rnew - (float)nh) * LO_SCALE);
      }
      af[s] = h; af[8 + s] = lo;
      if (nq == 0)
        *(f32x8*)&q1[(size_t)row * DDIM + s * 32 + li * 8] = qv;
      if (nq == 1)
        *(f32x8*)&q2[(size_t)row * DDIM + s * 32 + li * 8] = qv;
    }
  }

  // qsum = h - r_final (h re-read from untouched rext)
#pragma unroll
  for (int s = 0; s < 8; ++s) {
    const f16x8 hh = *(const f16x8*)&rext[(size_t)row * 512 + s * 32 + li * 8];
    const f16x8 hl = *(const f16x8*)&rext[(size_t)row * 512 + 256 + s * 32 + li * 8];
    f32x8 o;
#pragma unroll
    for (int i = 0; i < 8; ++i)
      o[i] = ((float)hh[i] + (float)hl[i] * LO_INV) -
             ((float)af[s][i] + (float)af[8 + s][i] * LO_INV);
    *(f32x8*)&qsum[(size_t)row * DDIM + s * 32 + li * 8] = o;
  }

  redc[tid] = csum;
  __syncthreads();
  for (int s = 256; s > 0; s >>= 1) {
    if (tid < s) redc[tid] += redc[tid + s];
    __syncthreads();
  }
  if (tid == 0) atomicAdd(commitAcc, redc[0]);
}

// ---------------------------------------------------------------------------
// Projection v3 (builtin MFMA — R9/R12/R13/R17/R19-bench-passing, unchanged).
// ---------------------------------------------------------------------------
template <int K, bool WEXT>
__global__ __launch_bounds__(512) void proj3(
    const float* __restrict__ A, const f16* __restrict__ Bext,
    const float* __restrict__ bias, float* __restrict__ Cout,
    f16* __restrict__ CextOut, int Ntot) {
  __shared__ __align__(16) f16 Bs[128][512];     // 128 KB
  const int tid = threadIdx.x;
  const int w = tid >> 6, l = tid & 63;
  const int lj = l & 15, li = l >> 4;
  const int m0 = blockIdx.x * 128;
  const int n0 = blockIdx.y * 128;
  const int row_t = m0 + w * 16 + lj;
  const int key = (lj & 7) << 4;

  f32x4 acc[8], acc2[8];
#pragma unroll
  for (int n = 0; n < 8; ++n) {
    acc[n] = (f32x4){0.f, 0.f, 0.f, 0.f};
    acc2[n] = (f32x4){0.f, 0.f, 0.f, 0.f};
  }

#pragma unroll 1
  for (int p = 0; p < K / 256; ++p) {
    __syncthreads();
#pragma unroll
    for (int q = 0; q < 16; ++q) {
      const int r = w * 16 + q;
      const int nrow = n0 + r;
      const int byteoff = (l * 16) ^ ((r & 7) << 4);
      const char* hi_base =
          (const char*)Bext + ((size_t)nrow * 2 * K + p * 256) * 2;
      const char* lo_base =
          (const char*)Bext + ((size_t)nrow * 2 * K + K + p * 256) * 2;
      const char* src = (byteoff < 512) ? hi_base + byteoff
                                        : lo_base + (byteoff - 512);
      __builtin_amdgcn_global_load_lds(
          (const __attribute__((address_space(1))) void*)src,
          (__attribute__((address_space(3))) void*)&Bs[r][0], 16, 0, 0);
    }
    f16x8 ahi[8], alo[8];
#pragma unroll
    for (int s = 0; s < 8; ++s) {
      const f32x8 v = *(const f32x8*)&A[(size_t)row_t * K + p * 256 + s * 32 + li * 8];
      f16x8 h, lo;
#pragma unroll
      for (int i = 0; i < 8; ++i) {
        const f16 hh = (f16)v[i];
        h[i] = hh;
        lo[i] = (f16)((v[i] - (float)hh) * LO_SCALE);
      }
      ahi[s] = h; alo[s] = lo;
    }
    __syncthreads();

#pragma unroll
    for (int t = 0; t < 12; ++t) {
      const int tl = (t < 4) ? t : (t < 8 ? t - 4 : t - 8);
      const int roff = (t < 4) ? 512 : 0;
#pragma unroll
      for (int n = 0; n < 8; ++n) {
        const int rr = n * 16 + lj;
#pragma unroll
        for (int kk = 0; kk < 2; ++kk) {
          const int boff = roff + tl * 128 + kk * 64 + li * 16;
          const f16x8 bf = *(const f16x8*)((const char*)&Bs[rr][0] + (boff ^ key));
          if (t < 4)
            acc2[n] = __builtin_amdgcn_mfma_f32_16x16x32_f16(ahi[2 * tl + kk], bf, acc2[n], 0, 0, 0);
          else if (t < 8)
            acc2[n] = __builtin_amdgcn_mfma_f32_16x16x32_f16(alo[2 * tl + kk], bf, acc2[n], 0, 0, 0);
          else
            acc[n] = __builtin_amdgcn_mfma_f32_16x16x32_f16(ahi[2 * tl + kk], bf, acc[n], 0, 0, 0);
        }
      }
    }
  }

#pragma unroll
  for (int n = 0; n < 8; ++n) {
    const int ncol = n0 + n * 16 + lj;
    const float bb = bias[ncol];
#pragma unroll
    for (int j = 0; j < 4; ++j) {
      const int tok = m0 + w * 16 + li * 4 + j;
      const float vv = acc[n][j] + acc2[n][j] * LO_INV + bb;
      if (WEXT) {
        const f16 hh = (f16)vv;
        CextOut[(size_t)tok * 512 + ncol] = hh;
        CextOut[(size_t)tok * 512 + 256 + ncol] = (f16)((vv - (float)hh) * LO_SCALE);
      } else {
        Cout[(size_t)tok * Ntot + ncol] = vv;
      }
    }
  }
}

extern "C" void kernel_launch(void* const* d_in, const int* in_sizes, int n_in,
                              void* d_out, int out_size, void* d_ws, size_t ws_size,
                              hipStream_t stream) {
  (void)in_sizes; (void)n_in; (void)out_size; (void)ws_size;
  const float* x     = (const float*)d_in[0];
  const float* W_in  = (const float*)d_in[1];
  const float* b_in  = (const float*)d_in[2];
  const float* W_out = (const float*)d_in[3];
  const float* b_out = (const float*)d_in[4];
  const float* cbs   = (const float*)d_in[5];

  float* out = (float*)d_out;                        // [BT, HIDDEN]
  float* q1  = out + (size_t)BT * HIDDEN;            // [BT, DDIM]
  float* q2  = q1 + (size_t)BT * DDIM;               // [BT, DDIM]
  float* com = q2 + (size_t)BT * DDIM;               // [1]

  f16*   rext      = (f16*)d_ws;                          // [BT][512]   32 MB
  float* qsum      = (float*)(rext + (size_t)BT * 512);   // [BT][256]   32 MB
  f16*   cbfrag    = (f16*)(qsum + (size_t)BT * DDIM);    // [8192][512]  8 MB
  f16*   W_inext   = cbfrag + (size_t)NQUANT * KCODE * 512; // [256][1024] 512 KB
  f16*   W_outext  = W_inext + (size_t)DDIM * 1024;        // [512][512]  512 KB
  float* cnorm     = (float*)(W_outext + (size_t)HIDDEN * 512);  // [NQ*K]
  float* commitAcc = cnorm + NQUANT * KCODE;
  unsigned* bar    = (unsigned*)(commitAcc + 1);

  cb_prep2<<<NQUANT * KCODE, 256, 0, stream>>>(cbs, cbfrag, cnorm);
  bext_conv<<<(DDIM * HIDDEN + 255) / 256, 256, 0, stream>>>(W_in, W_inext, DDIM, HIDDEN);
  bext_conv<<<(HIDDEN * DDIM + 255) / 256, 256, 0, stream>>>(W_out, W_outext, HIDDEN, DDIM);
  proj3<HIDDEN, true><<<dim3(BT / 128, DDIM / 128), 512, 0, stream>>>(
      x, W_inext, b_in, nullptr, rext, DDIM);
  zero2<<<1, 1, 0, stream>>>(commitAcc, bar);
  rvq_fused17<<<BT / 128, 512, 0, stream>>>(rext, cbfrag, cbs, cnorm,
                                            qsum, q1, q2, commitAcc, bar);
  proj3<DDIM, false><<<dim3(BT / 128, HIDDEN / 128), 512, 0, stream>>>(
      qsum, W_outext, b_out, out, nullptr, HIDDEN);
  finalize_com<<<1, 1, 0, stream>>>(commitAcc, com);
}